// Round 15
// baseline (35.801 us; speedup 1.0000x reference)
//
#include <hip/hip_runtime.h>
#include <hip/hip_bf16.h>
#include <math.h>

// Problem constants (fixed by setup_inputs)
constexpr int B_ = 16, S_ = 512, T_ = 4096, E_ = 256;

typedef __attribute__((ext_vector_type(8))) short short8;
typedef __attribute__((ext_vector_type(4))) float f32x4;

// Workspace layout (bytes)
constexpr size_t FLAGS_OFF = 0;                       // 1024 ints, written every call
constexpr size_t EWP_OFF   = 8192;                    // 8192x256 f32 = 8MB  (enc + enc@W)
constexpr size_t PEW_OFF   = 8192 + 8388608;          // 4096x256 f32 = 4MB  (PE@W + bpos)

// -ln(10000)/256
#define NEGC (-0.035977892f)

__device__ __forceinline__ unsigned pk_bf16(float a, float b) {
    __hip_bfloat162 h = __float22bfloat162_rn(make_float2(a, b));
    return *(unsigned*)&h;
}
__device__ __forceinline__ short bf16s(float x) {
    unsigned u = __float_as_uint(x);
    u += 0x7FFFu + ((u >> 16) & 1u);
    return (short)(u >> 16);
}
__device__ __forceinline__ float bf16f(short s) {
    return __uint_as_float(((unsigned)(unsigned short)s) << 16);
}

// ---------------------------------------------------------------------------
// k_pre: compute-bound producer.
//  bid <  512: EW' 64x64 tile = enc@W + enc(bf16)   [+ validation slice]
//  bid >= 512: PEW 64x64 tile = PE@W + bpos
// R5 MFMA core (2x2 of 32x32), R11 in-block W staging, R3 PE staging,
// LDS-transpose epilogue -> contiguous f32x4 row writes.
__global__ __launch_bounds__(256, 2) void k_pre(
    const float* __restrict__ enc, const float* __restrict__ W,
    const float* __restrict__ bpos,
    const int* __restrict__ align, const int* __restrict__ text,
    int* __restrict__ flags, float* __restrict__ ewp, float* __restrict__ pew)
{
    __shared__ __align__(16) short As[64 * 256];   // 32KB; later aliased as ew f32[64][68]
    __shared__ __align__(16) short Bs[64 * 256];   // 32KB

    const int tid = threadIdx.x;
    const int bid = blockIdx.x;
    const bool isPE = bid >= 512;
    const int m0 = (isPE ? (bid - 512) >> 2 : bid >> 2) << 6;
    const int n0 = (bid & 3) << 6;

    // ---- validation: disjoint 128-transition slice (bid < 512 covers all) ----
    if (!isPE && tid < 128) {
        const int id = bid * 128 + tid;
        const int t = id & (T_ - 1), b = id >> 12;
        int bad = 0;
        if (t > 0) {
            const int prev = (t - 1) >> 3;
            const int a = align[id];
            const int expct = (a == text[b * S_ + prev]) ? prev : min(prev + 1, S_ - 1);
            if ((t >> 3) != expct) bad = 1;
        }
        const int anybad = __any(bad) ? 1 : 0;
        if ((tid & 63) == 0) flags[bid * 2 + (tid >> 6)] = anybad;  // unconditional
    }

    // ---- stage As: enc rows (EW') or on-the-fly PE rows (PEW) ----
    {
        const int r = tid >> 2, c4 = tid & 3;
        if (!isPE) {
            const float* ap = enc + (size_t)(m0 + r) * E_;
#pragma unroll
            for (int jj = 0; jj < 8; ++jj) {
                const int seg = c4 + 4 * jj;
                float4 f0 = *(const float4*)(ap + seg * 8);
                float4 f1 = *(const float4*)(ap + seg * 8 + 4);
                union { short8 v8; unsigned u[4]; } cv;
                cv.u[0] = pk_bf16(f0.x, f0.y);
                cv.u[1] = pk_bf16(f0.z, f0.w);
                cv.u[2] = pk_bf16(f1.x, f1.y);
                cv.u[3] = pk_bf16(f1.z, f1.w);
                *(short8*)&As[(r * 256 + seg * 8) ^ ((r & 7) << 3)] = cv.v8;
            }
        } else {
            const float tf = (float)(m0 + r);
#pragma unroll
            for (int jj = 0; jj < 8; ++jj) {
                const int seg = c4 + 4 * jj;
                union { short8 v8; unsigned u[4]; } cv;
#pragma unroll
                for (int m = 0; m < 4; ++m) {
                    const int j2 = seg * 4 + m;
                    const float d = __expf((float)(2 * j2) * NEGC);
                    float s, c;
                    __sincosf(tf * d, &s, &c);
                    cv.u[m] = pk_bf16(s, c);
                }
                *(short8*)&As[(r * 256 + seg * 8) ^ ((r & 7) << 3)] = cv.v8;
            }
        }
    }
    // ---- stage Bs from fp32 W: cols [n0, n0+64), transpose + cvt ----
    {
        const int kk = tid >> 4;                   // 0..15
        const int nn = (tid & 15) * 4;             // 0..60
#pragma unroll
        for (int p = 0; p < 16; ++p) {
            const int k = p * 16 + kk;
            const float4 w4 = *(const float4*)(W + (size_t)k * E_ + n0 + nn);
            Bs[((nn + 0) * 256 + k) ^ (((nn + 0) & 7) << 3)] = bf16s(w4.x);
            Bs[((nn + 1) * 256 + k) ^ (((nn + 1) & 7) << 3)] = bf16s(w4.y);
            Bs[((nn + 2) * 256 + k) ^ (((nn + 2) & 7) << 3)] = bf16s(w4.z);
            Bs[((nn + 3) * 256 + k) ^ (((nn + 3) & 7) << 3)] = bf16s(w4.w);
        }
    }
    __syncthreads();

    // ---- MFMA: wave = 2x2 of 16x16-pairs (32x32 quadrant); R5-proven ----
    const int wid = tid >> 6, lane = tid & 63;
    const int q = lane >> 4, c = lane & 15;
    const int wm = (wid >> 1) << 5, wn = (wid & 1) << 5;
    f32x4 acc[2][2] = {{{0.f, 0.f, 0.f, 0.f}, {0.f, 0.f, 0.f, 0.f}},
                       {{0.f, 0.f, 0.f, 0.f}, {0.f, 0.f, 0.f, 0.f}}};
#pragma unroll
    for (int ks = 0; ks < 8; ++ks) {
        const int kidx = ks * 32 + q * 8;
        const int ra0 = wm + c, ra1 = wm + 16 + c;
        const int rb0 = wn + c, rb1 = wn + 16 + c;
        short8 a0 = *(const short8*)&As[(ra0 * 256 + kidx) ^ ((ra0 & 7) << 3)];
        short8 a1 = *(const short8*)&As[(ra1 * 256 + kidx) ^ ((ra1 & 7) << 3)];
        short8 b0 = *(const short8*)&Bs[(rb0 * 256 + kidx) ^ ((rb0 & 7) << 3)];
        short8 b1 = *(const short8*)&Bs[(rb1 * 256 + kidx) ^ ((rb1 & 7) << 3)];
        acc[0][0] = __builtin_amdgcn_mfma_f32_16x16x32_bf16(a0, b0, acc[0][0], 0, 0, 0);
        acc[0][1] = __builtin_amdgcn_mfma_f32_16x16x32_bf16(a0, b1, acc[0][1], 0, 0, 0);
        acc[1][0] = __builtin_amdgcn_mfma_f32_16x16x32_bf16(a1, b0, acc[1][0], 0, 0, 0);
        acc[1][1] = __builtin_amdgcn_mfma_f32_16x16x32_bf16(a1, b1, acc[1][1], 0, 0, 0);
    }

    // ---- EW': fold enc (bf16 from As) into acc; output col == As k-index ----
    if (!isPE) {
#pragma unroll
        for (int mt = 0; mt < 2; ++mt)
#pragma unroll
            for (int nh = 0; nh < 2; ++nh) {
                const int gc2 = n0 + wn + nh * 16 + c;
#pragma unroll
                for (int rr = 0; rr < 4; ++rr) {
                    const int r0 = wm + mt * 16 + q * 4 + rr;
                    acc[mt][nh][rr] += bf16f(As[(r0 * 256 + gc2) ^ ((r0 & 7) << 3)]);
                }
            }
    }

    // ---- transpose acc through LDS (D: row = 4q+rr, col = c); ew aliases As ----
    __syncthreads();
    float* ew = (float*)As;                        // [64][68]
#pragma unroll
    for (int mt = 0; mt < 2; ++mt)
#pragma unroll
        for (int nh = 0; nh < 2; ++nh)
#pragma unroll
            for (int rr = 0; rr < 4; ++rr)
                ew[(wm + mt * 16 + q * 4 + rr) * 68 + wn + nh * 16 + c] = acc[mt][nh][rr];
    __syncthreads();

    // ---- streaming epilogue: contiguous f32x4 rows ----
    const int c16 = tid & 15, rg = tid >> 4;
    float* const dst = isPE ? pew : ewp;
    f32x4 bi = {0.f, 0.f, 0.f, 0.f};
    if (isPE) bi = *(const f32x4*)(bpos + n0 + c16 * 4);
#pragma unroll
    for (int p = 0; p < 4; ++p) {
        const int row = rg + p * 16;
        f32x4 v = *(const f32x4*)&ew[row * 68 + c16 * 4];
        v += bi;
        *(f32x4*)(dst + (size_t)(m0 + row) * E_ + n0 + c16 * 4) = v;
    }
}

// ---------------------------------------------------------------------------
// k_expand: pure streaming writer (fill-kernel shape: no barriers in hot loop,
// no LDS traffic, low VGPR -> 32 waves/CU). One wave per output row:
// out[row,:] = EW'[b*512 + t/8, :] + PEW[t, :] + pitch*Wp + bpitch + emb_beats.
__global__ __launch_bounds__(256) void k_expand(
    const float* __restrict__ ewp, const float* __restrict__ pew,
    const float* __restrict__ pitch, const int* __restrict__ beats,
    const float* __restrict__ wpitch, const float* __restrict__ bpitch,
    const float* __restrict__ embb,
    const int* __restrict__ align, const int* __restrict__ text,
    const int* __restrict__ flags, float* __restrict__ out)
{
    __shared__ int s[4];
    const int tid = threadIdx.x;
    {
        const int4 f = ((const int4*)flags)[tid];    // 256 x int4 = 1024 flags
        const int o = f.x | f.y | f.z | f.w;
        const bool any = __any(o != 0);
        if ((tid & 63) == 0) s[tid >> 6] = any ? 1 : 0;
    }
    __syncthreads();
    const bool dirty = (s[0] | s[1] | s[2] | s[3]) != 0;

    const int wid = tid >> 6, lane = tid & 63;
    const f32x4 wp4 = *(const f32x4*)(wpitch + lane * 4);
    const f32x4 bp4 = *(const f32x4*)(bpitch + lane * 4);
    const f32x4 be0 = *(const f32x4*)(embb + lane * 4);
    const f32x4 be1 = *(const f32x4*)(embb + E_ + lane * 4);

#pragma unroll
    for (int it = 0; it < 8; ++it) {
        const int row = (blockIdx.x * 8 + it) * 4 + wid;   // 0..65535 = b*T + t
        const int b = row >> 12, t = row & (T_ - 1);
        int i = t >> 3;
        if (dirty) {                                   // cold exact path
            int ii = 0;
            for (int tt = 1; tt <= t; ++tt)
                if (align[b * T_ + tt] != text[b * S_ + ii]) ii = min(ii + 1, S_ - 1);
            i = ii;
        }
        const f32x4 e4 = *(const f32x4*)(ewp + (size_t)((b << 9) + i) * E_ + lane * 4);
        const f32x4 p4 = *(const f32x4*)(pew + (size_t)t * E_ + lane * 4);
        const float p = pitch[row];                    // wave-uniform broadcast
        const int bt = beats[row];
        const f32x4 be = bt ? be1 : be0;
        f32x4 o = e4 + p4 + p * wp4 + bp4 + be;
        __builtin_nontemporal_store(o, (f32x4*)(out + (size_t)row * E_ + lane * 4));
    }
}

// ---------------------------------------------------------------------------
extern "C" void kernel_launch(void* const* d_in, const int* in_sizes, int n_in,
                              void* d_out, int out_size, void* d_ws, size_t ws_size,
                              hipStream_t stream) {
    const float* enc    = (const float*)d_in[0];
    const int*   align  = (const int*)  d_in[1];
    const int*   text   = (const int*)  d_in[2];
    const float* pitch  = (const float*)d_in[3];
    const int*   beats  = (const int*)  d_in[4];
    const float* wpitch = (const float*)d_in[5];
    const float* bpitch = (const float*)d_in[6];
    const float* embb   = (const float*)d_in[7];
    const float* wpos   = (const float*)d_in[8];
    const float* bpos   = (const float*)d_in[9];
    float* out = (float*)d_out;

    char* ws = (char*)d_ws;
    int*   flags = (int*)  (ws + FLAGS_OFF);
    float* ewp   = (float*)(ws + EWP_OFF);
    float* pew   = (float*)(ws + PEW_OFF);

    hipLaunchKernelGGL(k_pre, dim3(768), dim3(256), 0, stream,
                       enc, wpos, bpos, align, text, flags, ewp, pew);
    hipLaunchKernelGGL(k_expand, dim3(2048), dim3(256), 0, stream,
                       ewp, pew, pitch, beats, wpitch, bpitch, embb,
                       align, text, flags, out);
}

// Round 16
// 22.943 us; speedup vs baseline: 1.5604x; 1.5604x over previous
//
#include <hip/hip_runtime.h>
#include <hip/hip_bf16.h>
#include <math.h>

// Problem constants (fixed by setup_inputs)
constexpr int B_ = 16, S_ = 512, T_ = 4096, E_ = 256;

typedef __attribute__((ext_vector_type(8))) short short8;
typedef __attribute__((ext_vector_type(4))) float f32x4;

// Workspace: 1024 validation flags (2 per fused block), written every call
constexpr size_t FLAGS_OFF = 0;

// -ln(10000)/256
#define NEGC (-0.035977892f)

__device__ __forceinline__ unsigned pk_bf16(float a, float b) {
    __hip_bfloat162 h = __float22bfloat162_rn(make_float2(a, b));
    return *(unsigned*)&h;
}
__device__ __forceinline__ short bf16s(float x) {
    unsigned u = __float_as_uint(x);
    u += 0x7FFFu + ((u >> 16) & 1u);
    return (short)(u >> 16);
}
__device__ __forceinline__ float bf16f(short s) {
    return __uint_as_float(((unsigned)(unsigned short)s) << 16);
}

// Raw barrier: LDS-visibility only — does NOT drain vmcnt, so global stores
// issued before it stay in flight (safe: no cross-wave reads of `out`).
__device__ __forceinline__ void rawbar() {
    asm volatile("s_waitcnt lgkmcnt(0)" ::: "memory");
    __builtin_amdgcn_s_barrier();
    __builtin_amdgcn_sched_barrier(0);
}

// ---------------------------------------------------------------------------
// Fused GEMM, single producer dispatch (empirical best, Round-11 source).
// Block = 4 phones x 16 batches x two 32-col chunks; grid (128,4); 2/CU.
// Inline: per-block validation slice of the aligner recurrence -> flags.
// Bs staged directly from fp32 W (transpose+cvt in-block; no prep kernel).
// enc folded into ew from LDS (epilogue has no enc re-read).
__global__ __launch_bounds__(256, 2) void k_fused(
    const float* __restrict__ enc, const float* __restrict__ W,
    const float* __restrict__ bpos,
    const float* __restrict__ pitch, const int* __restrict__ beats,
    const float* __restrict__ wpitch, const float* __restrict__ bpitch,
    const float* __restrict__ embb,
    const int* __restrict__ align, const int* __restrict__ text,
    int* __restrict__ flags, float* __restrict__ out)
{
    __shared__ __align__(16) short As[64 * 256];     // 32KB enc tile bf16 (persistent)
    __shared__ __align__(16) short Ps[32 * 256];     // 16KB PE rows bf16 (persistent)
    __shared__ __align__(16) short Bs[32 * 256];     // 16KB W^T chunk slice
    __shared__ __align__(16) float scratch[64 * 36]; // 9KB  pl then ew per chunk

    const int tid = threadIdx.x;
    const int i0 = blockIdx.x * 4;                   // phone base
    const int n0base = blockIdx.y * 64;
    const int t0base = i0 * 8;
    const int v = blockIdx.x * 4 + blockIdx.y;       // 0..511

    // ---- inline validation: disjoint 128-transition slice of the global
    // recurrence induction. All 512 blocks together cover all B*T ids. ----
    if (tid < 128) {
        const int id = v * 128 + tid;
        const int t = id & (T_ - 1), b = id >> 12;
        int bad = 0;
        if (t > 0) {
            const int prev = (t - 1) >> 3;
            const int a = align[id];
            const int expct = (a == text[b * S_ + prev]) ? prev : min(prev + 1, S_ - 1);
            if ((t >> 3) != expct) bad = 1;
        }
        const int anybad = __any(bad) ? 1 : 0;
        if ((tid & 63) == 0) flags[v * 2 + (tid >> 6)] = anybad;  // unconditional
    }

    // ---- stage As = enc rows 0..63 (row r: b = r>>2, phone = i0 + (r&3)) ----
    {
        const int r = tid >> 2, c4 = tid & 3;
        const float* ap = enc + (size_t)((r >> 2) * S_ + i0 + (r & 3)) * E_;
#pragma unroll
        for (int jj = 0; jj < 8; ++jj) {
            const int seg = c4 + 4 * jj;
            float4 f0 = *(const float4*)(ap + seg * 8);
            float4 f1 = *(const float4*)(ap + seg * 8 + 4);
            union { short8 v8; unsigned u[4]; } cv;
            cv.u[0] = pk_bf16(f0.x, f0.y);
            cv.u[1] = pk_bf16(f0.z, f0.w);
            cv.u[2] = pk_bf16(f1.x, f1.y);
            cv.u[3] = pk_bf16(f1.z, f1.w);
            *(short8*)&As[(r * 256 + seg * 8) ^ ((r & 7) << 3)] = cv.v8;
        }
    }
    // ---- stage Ps = PE rows 0..31 (on-the-fly sincos) ----
    {
        const int r = tid >> 3, c8 = tid & 7;
        const float tf = (float)(t0base + r);
#pragma unroll
        for (int jj = 0; jj < 4; ++jj) {
            const int seg = c8 * 4 + jj;
            union { short8 v8; unsigned u[4]; } cv;
#pragma unroll
            for (int m = 0; m < 4; ++m) {
                const int j2 = seg * 4 + m;
                const float d = __expf((float)(2 * j2) * NEGC);
                float s, c;
                __sincosf(tf * d, &s, &c);
                cv.u[m] = pk_bf16(s, c);
            }
            *(short8*)&Ps[(r * 256 + seg * 8) ^ ((r & 7) << 3)] = cv.v8;
        }
    }

    const int wid = tid >> 6, lane = tid & 63;
    const int q = lane >> 4, c = lane & 15;
    const int c8q = tid & 7, rgrp = tid >> 3;        // epilogue thread map
    const int j = rgrp & 3;                          // phone offset
    float* const pl = scratch;                       // [4][16][16] patches
    float* const ew = scratch;                       // [64][36] after pl consumed

#pragma unroll
    for (int chunk = 0; chunk < 2; ++chunk) {
        const int n0 = n0base + chunk * 32;

        // ---- stage Bs from fp32 W: transpose + cvt in-block ----
        // pass: 8 lanes share k-row, read 128B coalesced; write b16 transposed.
        {
            const int kk = tid >> 3;                 // 0..31 (k offset within pass)
            const int nn = (tid & 7) * 4;            // relative n (0..28)
#pragma unroll
            for (int p = 0; p < 8; ++p) {
                const int k = p * 32 + kk;
                const float4 w4 = *(const float4*)(W + (size_t)k * E_ + n0 + nn);
                const short b0 = bf16s(w4.x), b1 = bf16s(w4.y);
                const short b2 = bf16s(w4.z), b3 = bf16s(w4.w);
                Bs[((nn + 0) * 256 + k) ^ (((nn + 0) & 7) << 3)] = b0;
                Bs[((nn + 1) * 256 + k) ^ (((nn + 1) & 7) << 3)] = b1;
                Bs[((nn + 2) * 256 + k) ^ (((nn + 2) & 7) << 3)] = b2;
                Bs[((nn + 3) * 256 + k) ^ (((nn + 3) & 7) << 3)] = b3;
            }
        }
        if (chunk == 0) __syncthreads(); else rawbar();   // staging visible

        // ---- phase 1 MFMA: 32x32 PEW slice, wave (tq, nq) = 16t x 16n ----
        {
            const int tq = wid >> 1, nqp = wid & 1;
            const int ar = tq * 16 + c;
            const int br = nqp * 16 + c;
            f32x4 p = {0.f, 0.f, 0.f, 0.f};
#pragma unroll
            for (int ks = 0; ks < 8; ++ks) {
                const int kidx = ks * 32 + q * 8;
                short8 a = *(const short8*)&Ps[(ar * 256 + kidx) ^ ((ar & 7) << 3)];
                short8 b = *(const short8*)&Bs[(br * 256 + kidx) ^ ((br & 7) << 3)];
                p = __builtin_amdgcn_mfma_f32_16x16x32_bf16(a, b, p, 0, 0, 0);
            }
#pragma unroll
            for (int rr = 0; rr < 4; ++rr)
                pl[(tq * 2 + nqp) * 256 + (q * 4 + rr) * 16 + c] = p[rr];
        }
        if (chunk == 0) __syncthreads(); else rawbar();   // pl visible

        // ---- phase 2 MFMA: wave (mq, nq) = 32 enc-rows x 16 cols ----
        const int mq = wid >> 1, nq = wid & 1;
        const int ra0 = mq * 32 + c, ra1 = ra0 + 16;
        const int rb = nq * 16 + c;
        f32x4 acc0 = {0.f, 0.f, 0.f, 0.f}, acc1 = {0.f, 0.f, 0.f, 0.f};
#pragma unroll
        for (int ks = 0; ks < 8; ++ks) {
            const int kidx = ks * 32 + q * 8;
            short8 a0 = *(const short8*)&As[(ra0 * 256 + kidx) ^ ((ra0 & 7) << 3)];
            short8 a1 = *(const short8*)&As[(ra1 * 256 + kidx) ^ ((ra1 & 7) << 3)];
            short8 b  = *(const short8*)&Bs[(rb * 256 + kidx) ^ ((rb & 7) << 3)];
            acc0 = __builtin_amdgcn_mfma_f32_16x16x32_bf16(a0, b, acc0, 0, 0, 0);
            acc1 = __builtin_amdgcn_mfma_f32_16x16x32_bf16(a1, b, acc1, 0, 0, 0);
        }

        // ---- fold enc into acc (read back from As; saves epilogue e4 loads) ----
        {
            const int gc2 = n0 + nq * 16 + c;        // absolute output col = As k-index
#pragma unroll
            for (int rr = 0; rr < 4; ++rr) {
                const int r0 = mq * 32 + q * 4 + rr, r1 = r0 + 16;
                acc0[rr] += bf16f(As[(r0 * 256 + gc2) ^ ((r0 & 7) << 3)]);
                acc1[rr] += bf16f(As[(r1 * 256 + gc2) ^ ((r1 & 7) << 3)]);
            }
        }

        // ---- pv pre-read from pl + uniform epilogue loads ----
        const int gc = n0 + 4 * c8q;
        f32x4 pv[8];
#pragma unroll
        for (int d = 0; d < 8; ++d) {
            const int tl = j * 8 + d;
            pv[d] = *(const f32x4*)&pl[((tl >> 4) * 2 + (c8q >> 2)) * 256
                                       + (tl & 15) * 16 + ((4 * c8q) & 15)];
        }
        const f32x4 wp4 = *(const f32x4*)(wpitch + gc);
        const f32x4 cst = *(const f32x4*)(bpitch + gc) + *(const f32x4*)(bpos + gc);
        const f32x4 be0 = *(const f32x4*)(embb + gc);
        const f32x4 be1 = *(const f32x4*)(embb + E_ + gc);
        if (chunk == 0) __syncthreads(); else rawbar();   // all pl + Bs reads done

        // ---- transpose acc through LDS (D: row = 4q+rr, col = c); stride 36 ----
#pragma unroll
        for (int rr = 0; rr < 4; ++rr) {
            ew[(mq * 32 + q * 4 + rr) * 36 + nq * 16 + c]      = acc0[rr];
            ew[(mq * 32 + 16 + q * 4 + rr) * 36 + nq * 16 + c] = acc1[rr];
        }
        if (chunk == 0) __syncthreads(); else rawbar();   // ew visible

        // ---- epilogue: lane (rgrp, c8q); 2 row-passes x 8 frames; nt stores ----
#pragma unroll
        for (int p = 0; p < 2; ++p) {
            const int row = rgrp + 32 * p;
            const int bq = row >> 2;
            const size_t prow = (size_t)bq * T_ + t0base + j * 8;
            const float4 pi0 = *(const float4*)(pitch + prow);
            const float4 pi1 = *(const float4*)(pitch + prow + 4);
            const int4  bt0 = *(const int4*)(beats + prow);
            const int4  bt1 = *(const int4*)(beats + prow + 4);
            const f32x4 ewv = *(const f32x4*)&ew[row * 36 + 4 * c8q];
            const f32x4 base = ewv + cst;
            const float pp[8] = {pi0.x, pi0.y, pi0.z, pi0.w, pi1.x, pi1.y, pi1.z, pi1.w};
            const int   bb[8] = {bt0.x, bt0.y, bt0.z, bt0.w, bt1.x, bt1.y, bt1.z, bt1.w};
#pragma unroll
            for (int d = 0; d < 8; ++d) {
                const f32x4 be = bb[d] ? be1 : be0;
                f32x4 o = base + pv[d] + pp[d] * wp4 + be;
                __builtin_nontemporal_store(o, (f32x4*)(out + (prow + d) * E_ + gc));
            }
        }
        if (chunk == 0) rawbar();   // scratch/Bs free for chunk 1; stores in flight
    }
}

// ---------------------------------------------------------------------------
// Fixup: reads the 1024 flags written by k_fused. Clean (always, for this
// data): instant exit. Dirty: fp32-exact full recompute of out.
__global__ __launch_bounds__(256) void k_fixup(
    const float* __restrict__ enc, const int* __restrict__ align,
    const int* __restrict__ text, const float* __restrict__ pitch,
    const int* __restrict__ beats, const float* __restrict__ wpitch,
    const float* __restrict__ bpitch, const float* __restrict__ embb,
    const float* __restrict__ W, const float* __restrict__ bpos,
    const int* __restrict__ flags, float* __restrict__ out)
{
    __shared__ int s[4];
    __shared__ int idxl[256];
    const int tid = threadIdx.x;
    {
        const int4 f = ((const int4*)flags)[tid];    // 256 x int4 = 1024 flags
        const int o = f.x | f.y | f.z | f.w;
        const bool any = __any(o != 0);
        if ((tid & 63) == 0) s[tid >> 6] = any ? 1 : 0;
    }
    __syncthreads();
    if (!(s[0] | s[1] | s[2] | s[3])) return;

    // ---- dirty path (never for this data): exact fp32 recompute ----
    const int b = blockIdx.x >> 4;
    const int tseg = (blockIdx.x & 15) * 256;
    if (tid == 0) {
        int i = 0;
        if (tseg == 0) idxl[0] = 0;
        for (int t = 1; t < tseg + 256; ++t) {
            if (align[b * T_ + t] != text[b * S_ + i]) i = min(i + 1, S_ - 1);
            if (t >= tseg) idxl[t - tseg] = i;
        }
    }
    __syncthreads();
    const int col = tid;
    for (int tt = 0; tt < 256; ++tt) {
        const int t = tseg + tt;
        const int i = idxl[tt];
        const float* erow = enc + (size_t)(b * S_ + i) * E_;
        float acc = 0.f;
        for (int k2 = 0; k2 < 128; ++k2) {
            const float d = __expf((float)(2 * k2) * NEGC);
            float sn, cs;
            __sincosf((float)t * d, &sn, &cs);
            acc += (erow[2 * k2] + sn) * W[(2 * k2) * E_ + col]
                 + (erow[2 * k2 + 1] + cs) * W[(2 * k2 + 1) * E_ + col];
        }
        const float p = pitch[(size_t)b * T_ + t];
        const float be = beats[(size_t)b * T_ + t] ? embb[E_ + col] : embb[col];
        out[((size_t)b * T_ + t) * E_ + col] =
            erow[col] + acc + bpos[col] + p * wpitch[col] + bpitch[col] + be;
    }
}

// ---------------------------------------------------------------------------
extern "C" void kernel_launch(void* const* d_in, const int* in_sizes, int n_in,
                              void* d_out, int out_size, void* d_ws, size_t ws_size,
                              hipStream_t stream) {
    const float* enc    = (const float*)d_in[0];
    const int*   align  = (const int*)  d_in[1];
    const int*   text   = (const int*)  d_in[2];
    const float* pitch  = (const float*)d_in[3];
    const int*   beats  = (const int*)  d_in[4];
    const float* wpitch = (const float*)d_in[5];
    const float* bpitch = (const float*)d_in[6];
    const float* embb   = (const float*)d_in[7];
    const float* wpos   = (const float*)d_in[8];
    const float* bpos   = (const float*)d_in[9];
    float* out = (float*)d_out;

    int* flags = (int*)((char*)d_ws + FLAGS_OFF);

    hipLaunchKernelGGL(k_fused, dim3(S_ / 4, 4), dim3(256), 0, stream,
                       enc, wpos, bpos, pitch, beats, wpitch, bpitch, embb,
                       align, text, flags, out);
    hipLaunchKernelGGL(k_fixup, dim3(256), dim3(256), 0, stream,
                       enc, align, text, pitch, beats, wpitch, bpitch, embb,
                       wpos, bpos, flags, out);
}